// Round 16
// baseline (23.700 us; speedup 1.0000x reference)
//
#include <hip/hip_runtime.h>
#include <math.h>

#define B 4
#define S 4096
#define N 4096
#define BLK 1024           // 16 waves, 1 block/CU (LDS 64 KB)
#define NW 16
#define W 2                // two 32-col B-frags -> 64 s per block
#define PASS 2048          // cloud pts per LDS pass per cloud
#define NPASS 2
#define JTW 4              // j-tiles (32 rows) per wave per pass = PASS/32/NW
#define NBLK 256           // (S/64) * B blocks
#define INF 3.4e38f
#define SCALE 1099511627776.0   // 2^40 fixed-point scale

typedef _Float16 f16x8  __attribute__((ext_vector_type(8)));
typedef float    f32x16 __attribute__((ext_vector_type(16)));

// Nano-kernel: zero the 4 u64 sums + counter (replaces hipMemsetAsync —
// R14 showed an in-graph 64B fill dispatch costs ~5-10us).
__global__ __launch_bounds__(64) void sdf_zero(unsigned long long* z)
{
    if (threadIdx.x < 8) z[threadIdx.x] = 0ull;
}

// 32x32x16 K-packed Gram MFMA (mapping verified R12/R13), full-N per block.
// A (cloud pt j): {-y0,-y1,-y2, hy_hi, hy_lo, 0,0,0}
// B (grid s, cols=lane&31): lanes<32 {x0,x1,x2,1,1,0,0,0}; lanes>=32 zero
// (kills A's k=8..15 garbage). D[j][s] = hy - x.y ; u = hx + min_j D.
// Tail: per-block sum of |sqrt(2u_p)-sqrt(2u_g)| over its 64 s ->
// deterministic u64 fixed-point atomicAdd; 256th block writes out[B].
__global__ __launch_bounds__(BLK) void sdf_mfma(
    const float* __restrict__ grid,   // [B,S,3]
    const float* __restrict__ gts,    // [B,N,3]
    const float* __restrict__ preds,  // [B,N,3]
    unsigned long long* __restrict__ sum,  // [4] sums + [4]=cnt
    float* __restrict__ out)               // [B]
{
    __shared__ float4 Ap[PASS];       // 32 KB
    __shared__ float4 Ag[PASS];       // 32 KB

    const int tid   = threadIdx.x;
    const int lane  = tid & 63;
    const int wv    = tid >> 6;       // 0..15
    const int l31   = lane & 31;
    const int stile = blockIdx.x;     // 64 tiles of 64 s
    const int b     = blockIdx.y;
    const int scol  = stile * 64;

    // ---- B-frags + hx ----
    const bool lo32 = (lane < 32);
    f16x8 bf[W];
    float hx[W];
    #pragma unroll
    for (int w = 0; w < W; ++w) {
        const float* xp = grid + ((size_t)b * S + scol + w * 32 + l31) * 3;
        float x0 = (float)(_Float16)xp[0];
        float x1 = (float)(_Float16)xp[1];
        float x2 = (float)(_Float16)xp[2];
        hx[w] = 0.5f * (x0 * x0 + x1 * x1 + x2 * x2);
        f16x8 bb = { (_Float16)x0, (_Float16)x1, (_Float16)x2,
                     (_Float16)1.f, (_Float16)1.f,
                     (_Float16)0.f, (_Float16)0.f, (_Float16)0.f };
        f16x8 z  = { (_Float16)0.f, (_Float16)0.f, (_Float16)0.f, (_Float16)0.f,
                     (_Float16)0.f, (_Float16)0.f, (_Float16)0.f, (_Float16)0.f };
        bf[w] = lo32 ? bb : z;
    }

    // ---- staging role: waves 0-7 preds, 8-15 gts; 4 pts/thread ----
    const bool doP = (tid < BLK / 2);
    const int  st  = tid & (BLK / 2 - 1);          // 0..511
    const float4* csrc = (const float4*)((doP ? preds : gts) + (size_t)b * N * 3);
    float4* Abuf = doP ? Ap : Ag;

    const f32x16 zc = { 0.f, 0.f, 0.f, 0.f, 0.f, 0.f, 0.f, 0.f,
                        0.f, 0.f, 0.f, 0.f, 0.f, 0.f, 0.f, 0.f };
    // split accumulators: two independent min chains per cloud per w
    float accpa[W], accpb[W], accga[W], accgb[W];
    #pragma unroll
    for (int w = 0; w < W; ++w) {
        accpa[w] = INF; accpb[w] = INF; accga[w] = INF; accgb[w] = INF;
    }

    for (int p = 0; p < NPASS; ++p) {
        if (p) __syncthreads();            // prior pass fully consumed
        // ---- stage + pack (3 coalesced float4 -> 4 A-frags) ----
        {
            const int fo = p * (PASS * 3 / 4) + 3 * st;
            const float4 r0 = csrc[fo], r1 = csrc[fo + 1], r2 = csrc[fo + 2];
            const float ys[4][3] = { { r0.x, r0.y, r0.z }, { r0.w, r1.x, r1.y },
                                     { r1.z, r1.w, r2.x }, { r2.y, r2.z, r2.w } };
            #pragma unroll
            for (int k = 0; k < 4; ++k) {
                float y0 = (float)(_Float16)ys[k][0];
                float y1 = (float)(_Float16)ys[k][1];
                float y2 = (float)(_Float16)ys[k][2];
                float hy = 0.5f * (y0 * y0 + y1 * y1 + y2 * y2);
                _Float16 hh = (_Float16)hy;
                _Float16 hl = (_Float16)(hy - (float)hh);
                f16x8 a = { (_Float16)(-y0), (_Float16)(-y1), (_Float16)(-y2),
                            hh, hl, (_Float16)0.f, (_Float16)0.f, (_Float16)0.f };
                *(f16x8*)&Abuf[4 * st + k] = a;
            }
        }
        __syncthreads();

        // ---- compute: wave's JTW j-tiles of 32 rows ----
        const char* app = (const char*)Ap + ((size_t)wv * JTW * 32 + l31) * 16;
        const char* agp = (const char*)Ag + ((size_t)wv * JTW * 32 + l31) * 16;
        #pragma unroll
        for (int jt = 0; jt < JTW; ++jt) {
            const f16x8 afp = *(const f16x8*)(app + jt * 512);
            const f16x8 afg = *(const f16x8*)(agp + jt * 512);
            #pragma unroll
            for (int w = 0; w < W; ++w) {
                f32x16 d = __builtin_amdgcn_mfma_f32_32x32x16_f16(afp, bf[w], zc, 0, 0, 0);
                float a0 = accpa[w], a1 = accpb[w];
                a0 = fminf(fminf(a0, d[0]),  d[1]);    // chain A: d[0..7]
                a0 = fminf(fminf(a0, d[2]),  d[3]);
                a0 = fminf(fminf(a0, d[4]),  d[5]);
                a0 = fminf(fminf(a0, d[6]),  d[7]);
                a1 = fminf(fminf(a1, d[8]),  d[9]);    // chain B: d[8..15]
                a1 = fminf(fminf(a1, d[10]), d[11]);
                a1 = fminf(fminf(a1, d[12]), d[13]);
                a1 = fminf(fminf(a1, d[14]), d[15]);
                accpa[w] = a0; accpb[w] = a1;
            }
            #pragma unroll
            for (int w = 0; w < W; ++w) {
                f32x16 d = __builtin_amdgcn_mfma_f32_32x32x16_f16(afg, bf[w], zc, 0, 0, 0);
                float a0 = accga[w], a1 = accgb[w];
                a0 = fminf(fminf(a0, d[0]),  d[1]);
                a0 = fminf(fminf(a0, d[2]),  d[3]);
                a0 = fminf(fminf(a0, d[4]),  d[5]);
                a0 = fminf(fminf(a0, d[6]),  d[7]);
                a1 = fminf(fminf(a1, d[8]),  d[9]);
                a1 = fminf(fminf(a1, d[10]), d[11]);
                a1 = fminf(fminf(a1, d[12]), d[13]);
                a1 = fminf(fminf(a1, d[14]), d[15]);
                accga[w] = a0; accgb[w] = a1;
            }
        }
        __syncthreads();   // all reads done before overwrite / sm reuse
    }

    // ---- cross-lane + cross-wave fold ----
    float* sm = (float*)Ap;   // [NW][2][64] = 8 KB (barrier above)
    #pragma unroll
    for (int w = 0; w < W; ++w) {
        const float ap = fminf(accpa[w], accpb[w]);
        const float ag = fminf(accga[w], accgb[w]);
        float mp = fminf(ap, __shfl_xor(ap, 32, 64));
        float mg = fminf(ag, __shfl_xor(ag, 32, 64));
        if (lo32) {
            sm[(wv * 2 + 0) * 64 + w * 32 + l31] = hx[w] + mp;
            sm[(wv * 2 + 1) * 64 + w * 32 + l31] = hx[w] + mg;
        }
    }
    __syncthreads();
    if (tid < 64) {
        float mp = INF, mg = INF;
        #pragma unroll
        for (int v = 0; v < NW; ++v) {
            mp = fminf(mp, sm[(v * 2 + 0) * 64 + tid]);
            mg = fminf(mg, sm[(v * 2 + 1) * 64 + tid]);
        }
        float v = fabsf(sqrtf(fmaxf(2.f * mp, 0.f)) - sqrtf(fmaxf(2.f * mg, 0.f)));
        v += __shfl_down(v, 32, 64);
        v += __shfl_down(v, 16, 64);
        v += __shfl_down(v, 8, 64);
        v += __shfl_down(v, 4, 64);
        v += __shfl_down(v, 2, 64);
        v += __shfl_down(v, 1, 64);
        if (tid == 0) {
            // deterministic fixed-point merge (integer adds commute exactly)
            const unsigned long long q = (unsigned long long)((double)v * SCALE);
            const unsigned long long old = atomicAdd(&sum[b], q);
            // data-dependent (+0) -> orders cnt-add after sum-add
            unsigned long long* cnt = &sum[4];
            const unsigned long long c =
                atomicAdd(cnt, 1ull + (old >> 62));
            if (c == (unsigned long long)(NBLK - 1)) {
                #pragma unroll
                for (int bb = 0; bb < B; ++bb) {
                    const unsigned long long sv = atomicAdd(&sum[bb], 0ull);
                    out[bb] = (float)((double)sv * (1.0 / (SCALE * (double)S)));
                }
            }
        }
    }
}

extern "C" void kernel_launch(void* const* d_in, const int* in_sizes, int n_in,
                              void* d_out, int out_size, void* d_ws, size_t ws_size,
                              hipStream_t stream) {
    const float* grid  = (const float*)d_in[0];
    const float* gts   = (const float*)d_in[1];
    const float* preds = (const float*)d_in[2];
    float* out = (float*)d_out;

    unsigned long long* sum = (unsigned long long*)d_ws;   // [4] + cnt + pad

    sdf_zero<<<1, 64, 0, stream>>>(sum);

    dim3 g1(S / 64, B);               // (64, 4) = 256 blocks, 1/CU
    sdf_mfma<<<g1, BLK, 0, stream>>>(grid, gts, preds, sum, out);
}